// Round 10
// baseline (2235.217 us; speedup 1.0000x reference)
//
#include <hip/hip_runtime.h>
#include <math.h>
#include <float.h>

#define NUM_CB 8
#define CB_SIZE 256
#define DIM 128
#define BT (16 * 16384)                  // 262144 tokens
#define Q_ELEMS ((size_t)BT * DIM)       // 33554432
#define I_ELEMS ((size_t)BT * NUM_CB)    // 2097152

#define TC 32                            // candidates per streamed tile
#define TILES_PER_CB (CB_SIZE / TC)      // 8
#define NTILES_TOT (NUM_CB * TILES_PER_CB) // 64
#define TILE_BYTES 16384                 // 2 planes x 32 cand x 16 slots x 16B

// Pass-A ambiguity margin (validated rounds 6-9).
#define MARGIN_A 1.5e-4f

typedef short  bf16x8 __attribute__((ext_vector_type(8)));
typedef float  f32x4  __attribute__((ext_vector_type(4)));

__device__ __forceinline__ unsigned short bf16_rne(float f) {
    unsigned int u = __float_as_uint(f);
    u = u + 0x7FFFu + ((u >> 16) & 1u);
    return (unsigned short)(u >> 16);
}
__device__ __forceinline__ float bf16_tof(unsigned short h) {
    return __uint_as_float(((unsigned int)h) << 16);
}

// ---------------------------------------------------------------------------
// VALIDATED np emulation (rounds 6-9): pairwise-8 sum-of-squares, no FMA.
// ---------------------------------------------------------------------------
__device__ __forceinline__ float np_sum_sq_128(const float* a) {
#pragma clang fp contract(off)
    float r0 = 0.f, r1 = 0.f, r2 = 0.f, r3 = 0.f,
          r4 = 0.f, r5 = 0.f, r6 = 0.f, r7 = 0.f;
#pragma unroll
    for (int i = 0; i < DIM; i += 8) {
        r0 = r0 + a[i + 0] * a[i + 0];
        r1 = r1 + a[i + 1] * a[i + 1];
        r2 = r2 + a[i + 2] * a[i + 2];
        r3 = r3 + a[i + 3] * a[i + 3];
        r4 = r4 + a[i + 4] * a[i + 4];
        r5 = r5 + a[i + 5] * a[i + 5];
        r6 = r6 + a[i + 6] * a[i + 6];
        r7 = r7 + a[i + 7] * a[i + 7];
    }
    return ((r0 + r1) + (r2 + r3)) + ((r4 + r5) + (r6 + r7));
}

// VALIDATED: reference distance = fl(fl(x_sq+e_sq) - fl(2*cross_seqfma)).
__device__ __forceinline__ float np_dist_lds(const float4* rb4, float xs,
                                             float esq_c,
                                             const float* __restrict__ e) {
#pragma clang fp contract(off)
    float acc = 0.f;
#pragma unroll
    for (int i = 0; i < 32; ++i) {
        float4 rv = rb4[i];
        float4 ev = *reinterpret_cast<const float4*>(e + 4 * i);
        acc = fmaf(rv.x, ev.x, acc);
        acc = fmaf(rv.y, ev.y, acc);
        acc = fmaf(rv.z, ev.z, acc);
        acc = fmaf(rv.w, ev.w, acc);
    }
    float S  = xs + esq_c;
    float t2 = 2.0f * acc;
    return S - t2;
}

__global__ void rvq_esq_kernel(const float* __restrict__ cb,
                               float* __restrict__ esq) {
    int i = blockIdx.x * blockDim.x + threadIdx.x;   // 0 .. 2047
    if (i >= NUM_CB * CB_SIZE) return;
    esq[i] = np_sum_sq_128(cb + (size_t)i * DIM);
}

// ---------------------------------------------------------------------------
// Precompute merged bf16 hi|lo tile image, in the EXACT swizzled LDS layout:
// img[t*1024 + plane*512 + cand*16 + (slot ^ (cand&15))], t = k*8 + T,
// codeword = t*32 + cand. One 16KB tile per (k,T); 1 MB total.
// ---------------------------------------------------------------------------
__global__ void rvq_split_kernel(const float* __restrict__ cb,
                                 bf16x8* __restrict__ g_img) {
    int idx = blockIdx.x * blockDim.x + threadIdx.x;   // 0 .. 32767
    if (idx >= NUM_CB * CB_SIZE * 16) return;
    int slot = idx & 15;
    int cand = (idx >> 4) & (TC - 1);
    int t    = idx >> 9;                  // 0..63
    const float* src = cb + ((size_t)t * TC + cand) * DIM + slot * 8;
    float4 a = *reinterpret_cast<const float4*>(src);
    float4 b = *reinterpret_cast<const float4*>(src + 4);
    float e[8] = {a.x, a.y, a.z, a.w, b.x, b.y, b.z, b.w};
    bf16x8 eh, el;
#pragma unroll
    for (int i = 0; i < 8; ++i) {
        unsigned short h = bf16_rne(e[i]);
        float rem = e[i] - bf16_tof(h);
        eh[i] = (short)h;
        el[i] = (short)bf16_rne(rem);
    }
    int ds = slot ^ (cand & 15);
    g_img[(size_t)t * 1024 + cand * 16 + ds]       = eh;
    g_img[(size_t)t * 1024 + 512 + cand * 16 + ds] = el;
}

// DMA one 16KB tile into LDS buffer nb: 4 x global_load_lds(16B) per wave.
__device__ __forceinline__ void stage_tile(const bf16x8* __restrict__ g_img,
                                           bf16x8 (*s_buf)[1024],
                                           int t, int nb, int wid, int lane) {
    const char* gt = (const char*)g_img + (size_t)t * TILE_BYTES
                     + wid * 4096 + lane * 16;
    const char* lb = (const char*)(&s_buf[nb][0]) + wid * 4096;  // wave-uniform
#pragma unroll
    for (int c = 0; c < 4; ++c) {
        __builtin_amdgcn_global_load_lds(
            (const __attribute__((address_space(1))) unsigned int*)(gt + c * 1024),
            (__attribute__((address_space(3))) unsigned int*)(lb + c * 1024),
            16, 0, 0);
    }
}

// ---------------------------------------------------------------------------
// Main kernel: 64 tokens/block (4 waves x 16), residual in VGPRs.
// 64 tiles streamed with double-buffered global_load_lds DMA, ONE barrier
// per tile; per-cb epilogue (reduce/gate/PassB/update) inside compute phase.
// ---------------------------------------------------------------------------
__global__ __launch_bounds__(256) void rvq_mfma_kernel(
    const float* __restrict__ z,
    const float* __restrict__ cb,
    const float* __restrict__ esq,
    const bf16x8* __restrict__ g_img,
    float* __restrict__ out_q,
    float* __restrict__ out_idx,
    double* __restrict__ loss_acc) {

    __shared__ bf16x8 s_buf[2][1024];                // 2 x 16KB double buffer
    __shared__ __align__(16) float s_rbuf[4][DIM];   // per-wave passB residual
    __shared__ float s_m1[4][16], s_m2[4][16];
    __shared__ int   s_cmin[4][16];
    __shared__ double wsum[4];

    const int tid  = threadIdx.x;
    const int wid  = tid >> 6;
    const int lane = tid & 63;
    const int lrow = lane & 15;       // token-in-wave (A) / candidate col (B,C)
    const int lq   = lane >> 4;       // k-chunk group
    const int tokw = blockIdx.x * 64 + wid * 16;
    const int tok  = tokw + lrow;

    // ---- residual chunks: r[s][i] = z[tok][32s + 8lq + i] ----
    float r[4][8];
    {
        const float* zp = z + (size_t)tok * DIM + 8 * lq;
#pragma unroll
        for (int s = 0; s < 4; ++s) {
            float4 a = *reinterpret_cast<const float4*>(zp + 32 * s);
            float4 b = *reinterpret_cast<const float4*>(zp + 32 * s + 4);
            r[s][0] = a.x; r[s][1] = a.y; r[s][2] = a.z; r[s][3] = a.w;
            r[s][4] = b.x; r[s][5] = b.y; r[s][6] = b.z; r[s][7] = b.w;
        }
    }

    // ---- bf16 hi/mid split of residual (re-done per cb in epilogue) ----
    bf16x8 ah[4], am[4];
#pragma unroll
    for (int s = 0; s < 4; ++s)
#pragma unroll
        for (int i = 0; i < 8; ++i) {
            unsigned short h = bf16_rne(r[s][i]);
            float rem = r[s][i] - bf16_tof(h);
            ah[s][i] = (short)h;
            am[s][i] = (short)bf16_rne(rem);
        }

    float m1[4], m2[4];
    int   i1[4];
#pragma unroll
    for (int j = 0; j < 4; ++j) { m1[j] = FLT_MAX; m2[j] = FLT_MAX; i1[j] = 0x7fffffff; }

    double lsum = 0.0;

    // ---- prologue: stage tile 0 ----
    stage_tile(g_img, s_buf, 0, 0, wid, lane);
    asm volatile("s_waitcnt vmcnt(0)" ::: "memory");
    __syncthreads();

    for (int t = 0; t < NTILES_TOT; ++t) {
        const int nb = t & 1;
        if (t + 1 < NTILES_TOT)
            stage_tile(g_img, s_buf, t + 1, nb ^ 1, wid, lane);   // prefetch

        const int k = t >> 3;
        const int T = t & 7;
        const float* esqk = esq + k * CB_SIZE;

#pragma unroll
        for (int ct = 0; ct < 2; ++ct) {      // 16-candidate column tiles
            const int cbase = ct * 16 + lrow;
            bf16x8 bh[4], bl[4];
#pragma unroll
            for (int s = 0; s < 4; ++s) {
                int ls = (4 * s + lq) ^ lrow;
                bh[s] = s_buf[nb][cbase * 16 + ls];
                bl[s] = s_buf[nb][512 + cbase * 16 + ls];
            }
            f32x4 acc0 = {0.f, 0.f, 0.f, 0.f};
            f32x4 acc1 = {0.f, 0.f, 0.f, 0.f};
            acc0 = __builtin_amdgcn_mfma_f32_16x16x32_bf16(ah[0], bh[0], acc0, 0, 0, 0);
            acc0 = __builtin_amdgcn_mfma_f32_16x16x32_bf16(ah[1], bh[1], acc0, 0, 0, 0);
            acc1 = __builtin_amdgcn_mfma_f32_16x16x32_bf16(ah[2], bh[2], acc1, 0, 0, 0);
            acc1 = __builtin_amdgcn_mfma_f32_16x16x32_bf16(ah[3], bh[3], acc1, 0, 0, 0);
            acc0 = __builtin_amdgcn_mfma_f32_16x16x32_bf16(am[0], bh[0], acc0, 0, 0, 0);
            acc0 = __builtin_amdgcn_mfma_f32_16x16x32_bf16(am[1], bh[1], acc0, 0, 0, 0);
            acc1 = __builtin_amdgcn_mfma_f32_16x16x32_bf16(am[2], bh[2], acc1, 0, 0, 0);
            acc1 = __builtin_amdgcn_mfma_f32_16x16x32_bf16(am[3], bh[3], acc1, 0, 0, 0);
            acc0 = __builtin_amdgcn_mfma_f32_16x16x32_bf16(ah[0], bl[0], acc0, 0, 0, 0);
            acc0 = __builtin_amdgcn_mfma_f32_16x16x32_bf16(ah[1], bl[1], acc0, 0, 0, 0);
            acc1 = __builtin_amdgcn_mfma_f32_16x16x32_bf16(ah[2], bl[2], acc1, 0, 0, 0);
            acc1 = __builtin_amdgcn_mfma_f32_16x16x32_bf16(ah[3], bl[3], acc1, 0, 0, 0);

            const int c = T * TC + ct * 16 + lrow;
            const float esq_c = esqk[c];
#pragma unroll
            for (int j = 0; j < 4; ++j) {
                float s = fmaf(-2.0f, acc0[j] + acc1[j], esq_c);
                if (s < m1[j]) {
                    m2[j] = m1[j]; m1[j] = s; i1[j] = c;
                } else if (s < m2[j]) {
                    m2[j] = s;
                }
            }
        }

        if (T == TILES_PER_CB - 1) {
            // ================= per-codebook epilogue (wave-internal) =======
            const float* cbk = cb + (size_t)k * CB_SIZE * DIM;

            // cross-lane top-2 lexicographic reduce within 16-lane group
#pragma unroll
            for (int d = 1; d < 16; d <<= 1) {
#pragma unroll
                for (int j = 0; j < 4; ++j) {
                    float om1 = __shfl_xor(m1[j], d);
                    float om2 = __shfl_xor(m2[j], d);
                    int   oi1 = __shfl_xor(i1[j], d);
                    bool ow = (om1 < m1[j]) || (om1 == m1[j] && oi1 < i1[j]);
                    float w1 = ow ? om1 : m1[j];
                    int   wi = ow ? oi1 : i1[j];
                    float lo = ow ? m1[j] : om1;
                    float w2 = fminf(fminf(m2[j], om2), lo);
                    m1[j] = w1; i1[j] = wi; m2[j] = w2;
                }
            }
            if (lrow < 4) {
                float wm1 = lrow == 0 ? m1[0] : lrow == 1 ? m1[1] : lrow == 2 ? m1[2] : m1[3];
                float wm2 = lrow == 0 ? m2[0] : lrow == 1 ? m2[1] : lrow == 2 ? m2[2] : m2[3];
                int   wc  = lrow == 0 ? i1[0] : lrow == 1 ? i1[1] : lrow == 2 ? i1[2] : i1[3];
                int tt = 4 * lq + lrow;
                s_m1[wid][tt] = wm1;
                s_m2[wid][tt] = wm2;
                s_cmin[wid][tt] = wc;
            }
            asm volatile("s_waitcnt lgkmcnt(0)" ::: "memory");

            // Pass B: exact np argmin for ambiguous tokens (validated)
            float g1 = s_m1[wid][lrow];
            float g2 = s_m2[wid][lrow];
            bool amb = (lane < 16) && !(g2 - g1 > MARGIN_A);
            unsigned long long mask = __ballot(amb);
            while (mask) {
                int srct = __ffsll(mask) - 1;
                mask &= mask - 1;
                if (lrow == srct) {
#pragma unroll
                    for (int s = 0; s < 4; ++s) {
                        float4* dst = reinterpret_cast<float4*>(
                            &s_rbuf[wid][32 * s + 8 * lq]);
                        dst[0] = make_float4(r[s][0], r[s][1], r[s][2], r[s][3]);
                        dst[1] = make_float4(r[s][4], r[s][5], r[s][6], r[s][7]);
                    }
                }
                asm volatile("s_waitcnt lgkmcnt(0)" ::: "memory");
                float xs = 0.f;
                if (lane == 0) xs = np_sum_sq_128(&s_rbuf[wid][0]);
                xs = __shfl(xs, 0);
                const float4* rb4 = reinterpret_cast<const float4*>(&s_rbuf[wid][0]);
                float bd = FLT_MAX;
                int   bc = 0x7fffffff;
#pragma unroll
                for (int ii = 0; ii < 4; ++ii) {
                    int c = lane + 64 * ii;
                    float dref = np_dist_lds(rb4, xs, esqk[c],
                                             cbk + (size_t)c * DIM);
                    if (dref < bd || (dref == bd && c < bc)) { bd = dref; bc = c; }
                }
#pragma unroll
                for (int d = 1; d < 64; d <<= 1) {
                    float od = __shfl_xor(bd, d);
                    int   oc = __shfl_xor(bc, d);
                    if (od < bd || (od == bd && oc < bc)) { bd = od; bc = oc; }
                }
                if (lane == 0) s_cmin[wid][srct] = bc;
                asm volatile("s_waitcnt lgkmcnt(0)" ::: "memory");
            }

            if (lane < 16)
                out_idx[(size_t)(tokw + lane) * NUM_CB + k] =
                    (float)s_cmin[wid][lane];

            // residual update + loss
            const int cm = s_cmin[wid][lrow];
            const float* ep = cbk + (size_t)cm * DIM + 8 * lq;
            float l0 = 0.f, l1 = 0.f, l2 = 0.f, l3 = 0.f;
#pragma unroll
            for (int s = 0; s < 4; ++s) {
                float4 ev0 = *reinterpret_cast<const float4*>(ep + 32 * s);
                float4 ev1 = *reinterpret_cast<const float4*>(ep + 32 * s + 4);
                float d0 = ev0.x - r[s][0], d1 = ev0.y - r[s][1];
                float d2 = ev0.z - r[s][2], d3 = ev0.w - r[s][3];
                float d4 = ev1.x - r[s][4], d5 = ev1.y - r[s][5];
                float d6 = ev1.z - r[s][6], d7 = ev1.w - r[s][7];
                l0 = fmaf(d0, d0, l0); l1 = fmaf(d1, d1, l1);
                l2 = fmaf(d2, d2, l2); l3 = fmaf(d3, d3, l3);
                l0 = fmaf(d4, d4, l0); l1 = fmaf(d5, d5, l1);
                l2 = fmaf(d6, d6, l2); l3 = fmaf(d7, d7, l3);
                r[s][0] -= ev0.x; r[s][1] -= ev0.y; r[s][2] -= ev0.z; r[s][3] -= ev0.w;
                r[s][4] -= ev1.x; r[s][5] -= ev1.y; r[s][6] -= ev1.z; r[s][7] -= ev1.w;
            }
            lsum += (double)((l0 + l1) + (l2 + l3));

            if (k < NUM_CB - 1) {   // re-split for next codebook
#pragma unroll
                for (int s = 0; s < 4; ++s)
#pragma unroll
                    for (int i = 0; i < 8; ++i) {
                        unsigned short h = bf16_rne(r[s][i]);
                        float rem = r[s][i] - bf16_tof(h);
                        ah[s][i] = (short)h;
                        am[s][i] = (short)bf16_rne(rem);
                    }
            }
#pragma unroll
            for (int j = 0; j < 4; ++j) {
                m1[j] = FLT_MAX; m2[j] = FLT_MAX; i1[j] = 0x7fffffff;
            }
            // ================= end epilogue ================================
        }

        asm volatile("s_waitcnt vmcnt(0)" ::: "memory");  // prefetch landed
        __syncthreads();                                  // buf[nb] free
    }

    // ---- quantized = z - r_final ----
    {
        const float* zp = z + (size_t)tok * DIM + 8 * lq;
        float* op = out_q + (size_t)tok * DIM + 8 * lq;
#pragma unroll
        for (int s = 0; s < 4; ++s) {
            float4 a = *reinterpret_cast<const float4*>(zp + 32 * s);
            float4 b = *reinterpret_cast<const float4*>(zp + 32 * s + 4);
            float4 qa = make_float4(a.x - r[s][0], a.y - r[s][1],
                                    a.z - r[s][2], a.w - r[s][3]);
            float4 qb = make_float4(b.x - r[s][4], b.y - r[s][5],
                                    b.z - r[s][6], b.w - r[s][7]);
            *reinterpret_cast<float4*>(op + 32 * s)     = qa;
            *reinterpret_cast<float4*>(op + 32 * s + 4) = qb;
        }
    }

    // ---- loss reduction ----
    for (int off = 32; off > 0; off >>= 1)
        lsum += __shfl_down(lsum, off, 64);
    if (lane == 0) wsum[wid] = lsum;
    __syncthreads();
    if (tid == 0)
        atomicAdd(loss_acc, (wsum[0] + wsum[1]) + (wsum[2] + wsum[3]));
}

__global__ void rvq_finalize_kernel(const double* __restrict__ loss_acc,
                                    float* __restrict__ out_loss) {
    out_loss[0] = (float)(1.25 * loss_acc[0] / (double)Q_ELEMS);
}

extern "C" void kernel_launch(void* const* d_in, const int* in_sizes, int n_in,
                              void* d_out, int out_size, void* d_ws, size_t ws_size,
                              hipStream_t stream) {
    const float* z  = (const float*)d_in[0];
    const float* cb = (const float*)d_in[1];

    float* out_q    = (float*)d_out;
    float* out_idx  = out_q + Q_ELEMS;
    float* out_loss = out_idx + I_ELEMS;

    double* loss_acc = (double*)d_ws;
    float*  esq      = (float*)((char*)d_ws + 256);
    bf16x8* g_img    = (bf16x8*)((char*)d_ws + 16384);   // 1 MB tile image

    hipMemsetAsync(loss_acc, 0, sizeof(double), stream);
    rvq_esq_kernel<<<(NUM_CB * CB_SIZE + 255) / 256, 256, 0, stream>>>(cb, esq);
    rvq_split_kernel<<<(NUM_CB * CB_SIZE * 16 + 255) / 256, 256, 0, stream>>>(
        cb, g_img);
    rvq_mfma_kernel<<<BT / 64, 256, 0, stream>>>(z, cb, esq, g_img,
                                                 out_q, out_idx, loss_acc);
    rvq_finalize_kernel<<<1, 1, 0, stream>>>(loss_acc, out_loss);
}

// Round 11
// 1787.370 us; speedup vs baseline: 1.2506x; 1.2506x over previous
//
#include <hip/hip_runtime.h>
#include <math.h>
#include <float.h>

#define NUM_CB 8
#define CB_SIZE 256
#define DIM 128
#define BT (16 * 16384)                  // 262144 tokens
#define Q_ELEMS ((size_t)BT * DIM)       // 33554432
#define I_ELEMS ((size_t)BT * NUM_CB)    // 2097152

#define TC 32                            // candidates per streamed tile
#define TILES_PER_CB (CB_SIZE / TC)      // 8
#define NTILES_TOT (NUM_CB * TILES_PER_CB) // 64
#define TILE_BYTES 16384                 // 2 planes x 32 cand x 16 slots x 16B

// Pass-A ambiguity margin (validated rounds 6-10). Do not shrink.
#define MARGIN_A 1.5e-4f

typedef short  bf16x8 __attribute__((ext_vector_type(8)));
typedef float  f32x4  __attribute__((ext_vector_type(4)));

__device__ __forceinline__ unsigned short bf16_rne(float f) {
    unsigned int u = __float_as_uint(f);
    u = u + 0x7FFFu + ((u >> 16) & 1u);
    return (unsigned short)(u >> 16);
}
__device__ __forceinline__ float bf16_tof(unsigned short h) {
    return __uint_as_float(((unsigned int)h) << 16);
}

// ---------------------------------------------------------------------------
// VALIDATED np emulation (rounds 6-10): pairwise-8 sum-of-squares, no FMA.
// ---------------------------------------------------------------------------
__device__ __forceinline__ float np_sum_sq_128(const float* a) {
#pragma clang fp contract(off)
    float r0 = 0.f, r1 = 0.f, r2 = 0.f, r3 = 0.f,
          r4 = 0.f, r5 = 0.f, r6 = 0.f, r7 = 0.f;
#pragma unroll
    for (int i = 0; i < DIM; i += 8) {
        r0 = r0 + a[i + 0] * a[i + 0];
        r1 = r1 + a[i + 1] * a[i + 1];
        r2 = r2 + a[i + 2] * a[i + 2];
        r3 = r3 + a[i + 3] * a[i + 3];
        r4 = r4 + a[i + 4] * a[i + 4];
        r5 = r5 + a[i + 5] * a[i + 5];
        r6 = r6 + a[i + 6] * a[i + 6];
        r7 = r7 + a[i + 7] * a[i + 7];
    }
    return ((r0 + r1) + (r2 + r3)) + ((r4 + r5) + (r6 + r7));
}

__global__ void rvq_esq_kernel(const float* __restrict__ cb,
                               float* __restrict__ esq) {
    int i = blockIdx.x * blockDim.x + threadIdx.x;   // 0 .. 2047
    if (i >= NUM_CB * CB_SIZE) return;
    esq[i] = np_sum_sq_128(cb + (size_t)i * DIM);
}

// esq packed for per-lane register preload:
// esq_pk[((k*4 + m4)*64 + lane)*4 + j] = esq[k][16*(4*m4+j) + (lane&15)]
__global__ void rvq_esqpk_kernel(const float* __restrict__ esq,
                                 float* __restrict__ esq_pk) {
    int idx = blockIdx.x * blockDim.x + threadIdx.x;   // 0 .. 8191
    if (idx >= NUM_CB * 4 * 64 * 4) return;
    int j    = idx & 3;
    int lane = (idx >> 2) & 63;
    int m4   = (idx >> 8) & 3;
    int k    = idx >> 10;
    esq_pk[idx] = esq[k * CB_SIZE + 16 * (4 * m4 + j) + (lane & 15)];
}

// Transposed f32 codebook for coalesced Pass-B reads: cbT[k][d][c]
__global__ void rvq_transpose_kernel(const float* __restrict__ cb,
                                     float* __restrict__ cbT) {
    int idx = blockIdx.x * blockDim.x + threadIdx.x;   // 0 .. 262143
    if (idx >= NUM_CB * DIM * CB_SIZE) return;
    int c = idx & (CB_SIZE - 1);
    int d = (idx >> 8) & (DIM - 1);
    int k = idx >> 15;
    cbT[idx] = cb[((size_t)(k * CB_SIZE + c)) * DIM + d];
}

// ---------------------------------------------------------------------------
// Precompute merged bf16 hi|lo tile image in the EXACT swizzled LDS layout:
// img[t*1024 + plane*512 + cand*16 + (slot ^ (cand&15))], t = k*8 + T.
// ---------------------------------------------------------------------------
__global__ void rvq_split_kernel(const float* __restrict__ cb,
                                 bf16x8* __restrict__ g_img) {
    int idx = blockIdx.x * blockDim.x + threadIdx.x;   // 0 .. 32767
    if (idx >= NUM_CB * CB_SIZE * 16) return;
    int slot = idx & 15;
    int cand = (idx >> 4) & (TC - 1);
    int t    = idx >> 9;                  // 0..63
    const float* src = cb + ((size_t)t * TC + cand) * DIM + slot * 8;
    float4 a = *reinterpret_cast<const float4*>(src);
    float4 b = *reinterpret_cast<const float4*>(src + 4);
    float e[8] = {a.x, a.y, a.z, a.w, b.x, b.y, b.z, b.w};
    bf16x8 eh, el;
#pragma unroll
    for (int i = 0; i < 8; ++i) {
        unsigned short h = bf16_rne(e[i]);
        float rem = e[i] - bf16_tof(h);
        eh[i] = (short)h;
        el[i] = (short)bf16_rne(rem);
    }
    int ds = slot ^ (cand & 15);
    g_img[(size_t)t * 1024 + cand * 16 + ds]       = eh;
    g_img[(size_t)t * 1024 + 512 + cand * 16 + ds] = el;
}

// DMA one 16KB tile into LDS buffer nb: 4 x global_load_lds(16B) per wave.
__device__ __forceinline__ void stage_tile(const bf16x8* __restrict__ g_img,
                                           bf16x8 (*s_buf)[1024],
                                           int t, int nb, int wid, int lane) {
    const char* gt = (const char*)g_img + (size_t)t * TILE_BYTES
                     + wid * 4096 + lane * 16;
    const char* lb = (const char*)(&s_buf[nb][0]) + wid * 4096;  // wave-uniform
#pragma unroll
    for (int c = 0; c < 4; ++c) {
        __builtin_amdgcn_global_load_lds(
            (const __attribute__((address_space(1))) unsigned int*)(gt + c * 1024),
            (__attribute__((address_space(3))) unsigned int*)(lb + c * 1024),
            16, 0, 0);
    }
}

// ---------------------------------------------------------------------------
// Main kernel: 64 tokens/block (4 waves x 16), residual in VGPRs.
// k-outer loop; T fully unrolled (static esqr indexing). Double-buffered DMA.
// Pass B: coalesced transposed-codebook exact np argmin.
// ---------------------------------------------------------------------------
__global__ __launch_bounds__(256) void rvq_mfma_kernel(
    const float* __restrict__ z,
    const float* __restrict__ cb,
    const float* __restrict__ cbT,
    const float* __restrict__ esq,
    const float* __restrict__ esq_pk,
    const bf16x8* __restrict__ g_img,
    float* __restrict__ out_q,
    float* __restrict__ out_idx,
    double* __restrict__ loss_acc) {

    __shared__ bf16x8 s_buf[2][1024];                // 2 x 16KB double buffer
    __shared__ __align__(16) float s_rbuf[4][DIM];   // per-wave passB residual
    __shared__ float s_m1[4][16], s_m2[4][16];
    __shared__ int   s_cmin[4][16];
    __shared__ double wsum[4];

    const int tid  = threadIdx.x;
    const int wid  = tid >> 6;
    const int lane = tid & 63;
    const int lrow = lane & 15;       // candidate col (B,C) / token writer idx
    const int lq   = lane >> 4;       // k-chunk group
    const int tokw = blockIdx.x * 64 + wid * 16;
    const int tok  = tokw + lrow;

    // ---- residual chunks: r[s][i] = z[tok][32s + 8lq + i] ----
    float r[4][8];
    {
        const float* zp = z + (size_t)tok * DIM + 8 * lq;
#pragma unroll
        for (int s = 0; s < 4; ++s) {
            float4 a = *reinterpret_cast<const float4*>(zp + 32 * s);
            float4 b = *reinterpret_cast<const float4*>(zp + 32 * s + 4);
            r[s][0] = a.x; r[s][1] = a.y; r[s][2] = a.z; r[s][3] = a.w;
            r[s][4] = b.x; r[s][5] = b.y; r[s][6] = b.z; r[s][7] = b.w;
        }
    }

    bf16x8 ah[4], am[4];
#pragma unroll
    for (int s = 0; s < 4; ++s)
#pragma unroll
        for (int i = 0; i < 8; ++i) {
            unsigned short h = bf16_rne(r[s][i]);
            float rem = r[s][i] - bf16_tof(h);
            ah[s][i] = (short)h;
            am[s][i] = (short)bf16_rne(rem);
        }

    double lsum = 0.0;

    // prologue: stage tile 0
    stage_tile(g_img, s_buf, 0, 0, wid, lane);
    asm volatile("s_waitcnt vmcnt(0)" ::: "memory");
    __syncthreads();

    for (int k = 0; k < NUM_CB; ++k) {
        const float* esqk = esq + k * CB_SIZE;
        const float* cbk  = cb  + (size_t)k * CB_SIZE * DIM;

        // preload this cb's per-lane esq values (coalesced 16B/lane x4)
        float esqr[16];
        {
            const float4* ep4 = reinterpret_cast<const float4*>(esq_pk)
                                + (size_t)k * 4 * 64 + lane;
#pragma unroll
            for (int m4 = 0; m4 < 4; ++m4) {
                float4 v = ep4[m4 * 64];
                esqr[4 * m4 + 0] = v.x; esqr[4 * m4 + 1] = v.y;
                esqr[4 * m4 + 2] = v.z; esqr[4 * m4 + 3] = v.w;
            }
        }

        float m1[4], m2[4];
        int   i1[4];
#pragma unroll
        for (int j = 0; j < 4; ++j) { m1[j] = FLT_MAX; m2[j] = FLT_MAX; i1[j] = 0x7fffffff; }

#pragma unroll
        for (int T = 0; T < TILES_PER_CB; ++T) {
            const int t  = k * TILES_PER_CB + T;
            const int nb = T & 1;
            if (k < NUM_CB - 1 || T < TILES_PER_CB - 1)
                stage_tile(g_img, s_buf, t + 1, nb ^ 1, wid, lane);

#pragma unroll
            for (int ct = 0; ct < 2; ++ct) {      // 16-candidate column tiles
                const int cbase = ct * 16 + lrow;
                bf16x8 bh[4], bl[4];
#pragma unroll
                for (int s = 0; s < 4; ++s) {
                    int ls = (4 * s + lq) ^ lrow;
                    bh[s] = s_buf[nb][cbase * 16 + ls];
                    bl[s] = s_buf[nb][512 + cbase * 16 + ls];
                }
                f32x4 acc0 = {0.f, 0.f, 0.f, 0.f};
                f32x4 acc1 = {0.f, 0.f, 0.f, 0.f};
                acc0 = __builtin_amdgcn_mfma_f32_16x16x32_bf16(ah[0], bh[0], acc0, 0, 0, 0);
                acc0 = __builtin_amdgcn_mfma_f32_16x16x32_bf16(ah[1], bh[1], acc0, 0, 0, 0);
                acc1 = __builtin_amdgcn_mfma_f32_16x16x32_bf16(ah[2], bh[2], acc1, 0, 0, 0);
                acc1 = __builtin_amdgcn_mfma_f32_16x16x32_bf16(ah[3], bh[3], acc1, 0, 0, 0);
                acc0 = __builtin_amdgcn_mfma_f32_16x16x32_bf16(am[0], bh[0], acc0, 0, 0, 0);
                acc0 = __builtin_amdgcn_mfma_f32_16x16x32_bf16(am[1], bh[1], acc0, 0, 0, 0);
                acc1 = __builtin_amdgcn_mfma_f32_16x16x32_bf16(am[2], bh[2], acc1, 0, 0, 0);
                acc1 = __builtin_amdgcn_mfma_f32_16x16x32_bf16(am[3], bh[3], acc1, 0, 0, 0);
                acc0 = __builtin_amdgcn_mfma_f32_16x16x32_bf16(ah[0], bl[0], acc0, 0, 0, 0);
                acc0 = __builtin_amdgcn_mfma_f32_16x16x32_bf16(ah[1], bl[1], acc0, 0, 0, 0);
                acc1 = __builtin_amdgcn_mfma_f32_16x16x32_bf16(ah[2], bl[2], acc1, 0, 0, 0);
                acc1 = __builtin_amdgcn_mfma_f32_16x16x32_bf16(ah[3], bl[3], acc1, 0, 0, 0);

                const int c = T * TC + ct * 16 + lrow;
                const float esq_c = esqr[T * 2 + ct];   // static index
#pragma unroll
                for (int j = 0; j < 4; ++j) {
                    float s = fmaf(-2.0f, acc0[j] + acc1[j], esq_c);
                    if (s < m1[j]) {
                        m2[j] = m1[j]; m1[j] = s; i1[j] = c;
                    } else if (s < m2[j]) {
                        m2[j] = s;
                    }
                }
            }

            if (T == TILES_PER_CB - 1) {
                // ============== per-codebook epilogue (wave-internal) ======
#pragma unroll
                for (int d = 1; d < 16; d <<= 1) {
#pragma unroll
                    for (int j = 0; j < 4; ++j) {
                        float om1 = __shfl_xor(m1[j], d);
                        float om2 = __shfl_xor(m2[j], d);
                        int   oi1 = __shfl_xor(i1[j], d);
                        bool ow = (om1 < m1[j]) || (om1 == m1[j] && oi1 < i1[j]);
                        float w1 = ow ? om1 : m1[j];
                        int   wi = ow ? oi1 : i1[j];
                        float lo = ow ? m1[j] : om1;
                        float w2 = fminf(fminf(m2[j], om2), lo);
                        m1[j] = w1; i1[j] = wi; m2[j] = w2;
                    }
                }
                if (lrow < 4) {
                    float wm1 = lrow == 0 ? m1[0] : lrow == 1 ? m1[1] : lrow == 2 ? m1[2] : m1[3];
                    float wm2 = lrow == 0 ? m2[0] : lrow == 1 ? m2[1] : lrow == 2 ? m2[2] : m2[3];
                    int   wc  = lrow == 0 ? i1[0] : lrow == 1 ? i1[1] : lrow == 2 ? i1[2] : i1[3];
                    int tt = 4 * lq + lrow;
                    s_m1[wid][tt] = wm1;
                    s_m2[wid][tt] = wm2;
                    s_cmin[wid][tt] = wc;
                }
                asm volatile("s_waitcnt lgkmcnt(0)" ::: "memory");

                // Pass B: exact np argmin, coalesced transposed reads
                float g1 = s_m1[wid][lrow];
                float g2 = s_m2[wid][lrow];
                bool amb = (lane < 16) && !(g2 - g1 > MARGIN_A);
                unsigned long long mask = __ballot(amb);
                while (mask) {
                    int srct = __ffsll(mask) - 1;
                    mask &= mask - 1;
                    if (lrow == srct) {
#pragma unroll
                        for (int s = 0; s < 4; ++s) {
                            float4* dst = reinterpret_cast<float4*>(
                                &s_rbuf[wid][32 * s + 8 * lq]);
                            dst[0] = make_float4(r[s][0], r[s][1], r[s][2], r[s][3]);
                            dst[1] = make_float4(r[s][4], r[s][5], r[s][6], r[s][7]);
                        }
                    }
                    asm volatile("s_waitcnt lgkmcnt(0)" ::: "memory");
                    float xs = 0.f;
                    if (lane == 0) xs = np_sum_sq_128(&s_rbuf[wid][0]);
                    xs = __shfl(xs, 0);

                    // 4 candidates/lane, sequential-fmaf chains (np order),
                    // loads coalesced: cbT[k][d][lane + 64*ii]
                    const float* cbTk = cbT + (size_t)k * DIM * CB_SIZE + lane;
                    const float* rb = &s_rbuf[wid][0];
                    float a0 = 0.f, a1 = 0.f, a2 = 0.f, a3 = 0.f;
#pragma unroll 8
                    for (int d = 0; d < DIM; ++d) {
                        float rv = rb[d];
                        const float* row = cbTk + (size_t)d * CB_SIZE;
                        a0 = fmaf(rv, row[0],   a0);
                        a1 = fmaf(rv, row[64],  a1);
                        a2 = fmaf(rv, row[128], a2);
                        a3 = fmaf(rv, row[192], a3);
                    }
                    float dd0, dd1, dd2, dd3;
                    {
#pragma clang fp contract(off)
                        float S0 = xs + esqk[lane];
                        float S1 = xs + esqk[lane + 64];
                        float S2 = xs + esqk[lane + 128];
                        float S3 = xs + esqk[lane + 192];
                        dd0 = S0 - 2.0f * a0;
                        dd1 = S1 - 2.0f * a1;
                        dd2 = S2 - 2.0f * a2;
                        dd3 = S3 - 2.0f * a3;
                    }
                    float bd = dd0; int bc = lane;
                    if (dd1 < bd) { bd = dd1; bc = lane + 64; }
                    if (dd2 < bd) { bd = dd2; bc = lane + 128; }
                    if (dd3 < bd) { bd = dd3; bc = lane + 192; }
#pragma unroll
                    for (int d = 1; d < 64; d <<= 1) {
                        float od = __shfl_xor(bd, d);
                        int   oc = __shfl_xor(bc, d);
                        if (od < bd || (od == bd && oc < bc)) { bd = od; bc = oc; }
                    }
                    if (lane == 0) s_cmin[wid][srct] = bc;
                    asm volatile("s_waitcnt lgkmcnt(0)" ::: "memory");
                }

                if (lane < 16)
                    out_idx[(size_t)(tokw + lane) * NUM_CB + k] =
                        (float)s_cmin[wid][lane];

                // residual update + loss (gather from row-major cb)
                const int cm = s_cmin[wid][lrow];
                const float* ep = cbk + (size_t)cm * DIM + 8 * lq;
                float l0 = 0.f, l1 = 0.f, l2 = 0.f, l3 = 0.f;
#pragma unroll
                for (int s = 0; s < 4; ++s) {
                    float4 ev0 = *reinterpret_cast<const float4*>(ep + 32 * s);
                    float4 ev1 = *reinterpret_cast<const float4*>(ep + 32 * s + 4);
                    float d0 = ev0.x - r[s][0], d1 = ev0.y - r[s][1];
                    float d2 = ev0.z - r[s][2], d3 = ev0.w - r[s][3];
                    float d4 = ev1.x - r[s][4], d5 = ev1.y - r[s][5];
                    float d6 = ev1.z - r[s][6], d7 = ev1.w - r[s][7];
                    l0 = fmaf(d0, d0, l0); l1 = fmaf(d1, d1, l1);
                    l2 = fmaf(d2, d2, l2); l3 = fmaf(d3, d3, l3);
                    l0 = fmaf(d4, d4, l0); l1 = fmaf(d5, d5, l1);
                    l2 = fmaf(d6, d6, l2); l3 = fmaf(d7, d7, l3);
                    r[s][0] -= ev0.x; r[s][1] -= ev0.y; r[s][2] -= ev0.z; r[s][3] -= ev0.w;
                    r[s][4] -= ev1.x; r[s][5] -= ev1.y; r[s][6] -= ev1.z; r[s][7] -= ev1.w;
                }
                lsum += (double)((l0 + l1) + (l2 + l3));

                if (k < NUM_CB - 1) {   // re-split for next codebook
#pragma unroll
                    for (int s = 0; s < 4; ++s)
#pragma unroll
                        for (int i = 0; i < 8; ++i) {
                            unsigned short h = bf16_rne(r[s][i]);
                            float rem = r[s][i] - bf16_tof(h);
                            ah[s][i] = (short)h;
                            am[s][i] = (short)bf16_rne(rem);
                        }
                }
                // ============== end epilogue ===============================
            }

            asm volatile("s_waitcnt vmcnt(0)" ::: "memory");  // prefetch landed
            __syncthreads();                                  // buf[nb] free
        }
    }

    // ---- quantized = z - r_final ----
    {
        const float* zp = z + (size_t)tok * DIM + 8 * lq;
        float* op = out_q + (size_t)tok * DIM + 8 * lq;
#pragma unroll
        for (int s = 0; s < 4; ++s) {
            float4 a = *reinterpret_cast<const float4*>(zp + 32 * s);
            float4 b = *reinterpret_cast<const float4*>(zp + 32 * s + 4);
            float4 qa = make_float4(a.x - r[s][0], a.y - r[s][1],
                                    a.z - r[s][2], a.w - r[s][3]);
            float4 qb = make_float4(b.x - r[s][4], b.y - r[s][5],
                                    b.z - r[s][6], b.w - r[s][7]);
            *reinterpret_cast<float4*>(op + 32 * s)     = qa;
            *reinterpret_cast<float4*>(op + 32 * s + 4) = qb;
        }
    }

    // ---- loss reduction ----
    for (int off = 32; off > 0; off >>= 1)
        lsum += __shfl_down(lsum, off, 64);
    if (lane == 0) wsum[wid] = lsum;
    __syncthreads();
    if (tid == 0)
        atomicAdd(loss_acc, (wsum[0] + wsum[1]) + (wsum[2] + wsum[3]));
}

__global__ void rvq_finalize_kernel(const double* __restrict__ loss_acc,
                                    float* __restrict__ out_loss) {
    out_loss[0] = (float)(1.25 * loss_acc[0] / (double)Q_ELEMS);
}

extern "C" void kernel_launch(void* const* d_in, const int* in_sizes, int n_in,
                              void* d_out, int out_size, void* d_ws, size_t ws_size,
                              hipStream_t stream) {
    const float* z  = (const float*)d_in[0];
    const float* cb = (const float*)d_in[1];

    float* out_q    = (float*)d_out;
    float* out_idx  = out_q + Q_ELEMS;
    float* out_loss = out_idx + I_ELEMS;

    double* loss_acc = (double*)d_ws;
    float*  esq      = (float*)((char*)d_ws + 256);              // 8 KB
    float*  esq_pk   = (float*)((char*)d_ws + 16384);            // 32 KB
    bf16x8* g_img    = (bf16x8*)((char*)d_ws + 65536);           // 1 MB
    float*  cbT      = (float*)((char*)d_ws + 65536 + 1048576);  // 1 MB

    hipMemsetAsync(loss_acc, 0, sizeof(double), stream);
    rvq_esq_kernel<<<(NUM_CB * CB_SIZE + 255) / 256, 256, 0, stream>>>(cb, esq);
    rvq_esqpk_kernel<<<(NUM_CB * 4 * 64 * 4 + 255) / 256, 256, 0, stream>>>(
        esq, esq_pk);
    rvq_split_kernel<<<(NUM_CB * CB_SIZE * 16 + 255) / 256, 256, 0, stream>>>(
        cb, g_img);
    rvq_transpose_kernel<<<(NUM_CB * DIM * CB_SIZE + 255) / 256, 256, 0,
                           stream>>>(cb, cbT);
    rvq_mfma_kernel<<<BT / 64, 256, 0, stream>>>(z, cb, cbT, esq, esq_pk,
                                                 g_img, out_q, out_idx,
                                                 loss_acc);
    rvq_finalize_kernel<<<1, 1, 0, stream>>>(loss_acc, out_loss);
}